// Round 5
// baseline (484.448 us; speedup 1.0000x reference)
//
#include <hip/hip_runtime.h>
#include <hip/hip_bf16.h>

#define N_NODES 100000
#define N_EDGES 1600000
#define DIM 64
#define N_LAYERS 5
#define N_GRAPHS 256

#define NB2 391        // coarse buckets of 256 nodes (391*256 = 100096 >= 100000)
#define BSH 8          // bucket shift: node>>8
#define BMSK 255       // local id mask
#define SUBCAP2 4608   // per-bucket pair capacity: mean 4096, sigma ~64 (+8 sigma)
#define CAP2 6400      // esrc region per bucket (padded CSR: mean 4992, +19 sigma)
#define DUMMY N_NODES  // dummy node id; its h row is kept zero
#define TILE 3200      // edges per binning workgroup
#define NTILE 500      // 500 * 3200 = 1.6M
#define MTILES (N_NODES / 16)  // 6250 16-node tiles

#define CVT_BLOCKS 6250            // 6250*256*4 = 1.6M float4 = N_NODES*DIM
#define PREPACK_BLOCKS 40          // 40*256 = 10240 = N_LAYERS*32*64
#define SETUP_BLOCKS (CVT_BLOCKS + PREPACK_BLOCKS + 1)

typedef __attribute__((ext_vector_type(8))) short short8;
typedef __attribute__((ext_vector_type(4))) float float4v;

// bf16 helpers (bit-level, RNE)
__device__ __forceinline__ unsigned short f2bf(float f) {
    unsigned int u = __float_as_uint(f);
    unsigned int r = (u + 0x7fffu + ((u >> 16) & 1u)) >> 16;
    return (unsigned short)r;
}
__device__ __forceinline__ float bf2f(unsigned short b) {
    return __uint_as_float(((unsigned int)b) << 16);
}

// Merged setup: cvt (blocks 0..6249) | prepack (blocks 6250..6289) |
// bcursor-zero + dummy-row-zero (block 6290). All independent; one dispatch.
__global__ __launch_bounds__(256) void setup_kernel(
    const float4* __restrict__ x, ushort4* __restrict__ hb,
    const float* __restrict__ Ws1, const float* __restrict__ Ws2,
    unsigned short* __restrict__ wpk, int* __restrict__ bcursor,
    unsigned short* __restrict__ hA, unsigned short* __restrict__ hB) {
    const int b = blockIdx.x;
    const int tid = threadIdx.x;
    if (b < CVT_BLOCKS) {
        int i = b * 256 + tid;  // exactly N_NODES*DIM/4
        float4 v = x[i];
        ushort4 o;
        o.x = f2bf(v.x); o.y = f2bf(v.y); o.z = f2bf(v.z); o.w = f2bf(v.w);
        hb[i] = o;
    } else if (b < CVT_BLOCKS + PREPACK_BLOCKS) {
        int t = (b - CVT_BLOCKS) * 256 + tid;  // < N_LAYERS*32*64
        int lane = t & 63;
        int frag = (t >> 6) & 31;
        int l = t >> 11;
        int kf = frag & 1;
        int nt = (frag >> 1) & 3;
        int split = (frag >> 3) & 1;
        int mat = (frag >> 4) & 1;
        const float* W = (mat ? Ws2 : Ws1) + (size_t)l * DIM * DIM;
        unsigned short outv[8];
#pragma unroll
        for (int j = 0; j < 8; ++j) {
            int k = kf * 32 + ((lane >> 4) << 3) + j;
            int n = nt * 16 + (lane & 15);
            float v = W[k * DIM + n];
            unsigned short hi = f2bf(v);
            outv[j] = split ? f2bf(v - bf2f(hi)) : hi;
        }
        ushort4* dst = (ushort4*)(wpk + ((size_t)(l * 32 + frag) * 64 + lane) * 8);
        dst[0] = make_ushort4(outv[0], outv[1], outv[2], outv[3]);
        dst[1] = make_ushort4(outv[4], outv[5], outv[6], outv[7]);
    } else {
        for (int l = tid; l < NB2; l += 256) bcursor[l] = 0;
        if (tid < DIM) {
            hA[(size_t)DUMMY * DIM + tid] = 0;
            hB[(size_t)DUMMY * DIM + tid] = 0;
        }
    }
}

// Phase A: tile-binning with run reservation (one global atomic per bucket per tile).
__global__ __launch_bounds__(256) void bin_kernel(
    const int* __restrict__ src, const int* __restrict__ dst,
    int* __restrict__ bcursor, int* __restrict__ pairbuf) {
    __shared__ int hcnt[NB2];
    __shared__ int gbase[NB2];
    __shared__ int lcur[NB2];
    const int tid = threadIdx.x;
    const int base = blockIdx.x * TILE;

    for (int l = tid; l < NB2; l += 256) { hcnt[l] = 0; lcur[l] = 0; }
    __syncthreads();
    for (int j = tid; j < TILE; j += 256) {
        int d = dst[base + j];
        atomicAdd(&hcnt[d >> BSH], 1);
    }
    __syncthreads();
    for (int l = tid; l < NB2; l += 256)
        gbase[l] = atomicAdd(&bcursor[l], hcnt[l]);
    __syncthreads();
    for (int j = tid; j < TILE; j += 256) {
        int s = src[base + j];
        int d = dst[base + j];
        int b = d >> BSH;
        int r = atomicAdd(&lcur[b], 1);
        int pos = gbase[b] + r;
        if (pos < SUBCAP2) pairbuf[b * SUBCAP2 + pos] = (s << BSH) | (d & BMSK);
    }
}

// Phase B: one 512-thread WG per 256-node bucket. Count -> padded scan -> scatter.
__global__ __launch_bounds__(512) void csr_kernel(
    const int* __restrict__ bcursor, const int* __restrict__ pairbuf,
    int* __restrict__ esrc, int2* __restrict__ meta) {
    __shared__ int lcnt[256];
    __shared__ int loff[256];
    __shared__ int lcur[256];
    __shared__ int s2[256];
    const int b = blockIdx.x;
    const int tid = threadIdx.x;
    int ec = bcursor[b];
    if (ec > SUBCAP2) ec = SUBCAP2;
    const int* pp = pairbuf + b * SUBCAP2;

    if (tid < 256) lcnt[tid] = 0;
    __syncthreads();
    for (int j = tid; j < ec; j += 512) atomicAdd(&lcnt[pp[j] & BMSK], 1);
    __syncthreads();

    if (tid < 256) s2[tid] = (lcnt[tid] + 7) & ~7;
    __syncthreads();
    for (int off = 1; off < 256; off <<= 1) {
        int v = (tid >= off && tid < 256) ? s2[tid - off] : 0;
        __syncthreads();
        if (tid < 256) s2[tid] += v;
        __syncthreads();
    }
    if (tid < 256) {
        int c = (lcnt[tid] + 7) & ~7;
        int exc = s2[tid] - c;
        loff[tid] = exc;
        lcur[tid] = exc;
    }
    __syncthreads();

    int* eb = esrc + (size_t)b * CAP2;
    for (int l = tid; l < 256; l += 512) {
        int st = loff[l];
        int cn = lcnt[l];
        int cp = (cn + 7) & ~7;
        int node = b * 256 + l;
        if (node < N_NODES) meta[node] = make_int2(b * CAP2 + st, cp);
        for (int j = cn; j < cp; ++j) eb[st + j] = DUMMY;
    }
    __syncthreads();

    for (int j = tid; j < ec; j += 512) {
        int p = pp[j];
        int pos = atomicAdd(&lcur[p & BMSK], 1);
        eb[pos] = p >> BSH;
    }
}

__device__ __forceinline__ void acc8(float* acc, uint4 v) {
    acc[0] += __uint_as_float(v.x << 16);
    acc[1] += __uint_as_float(v.x & 0xffff0000u);
    acc[2] += __uint_as_float(v.y << 16);
    acc[3] += __uint_as_float(v.y & 0xffff0000u);
    acc[4] += __uint_as_float(v.z << 16);
    acc[5] += __uint_as_float(v.z & 0xffff0000u);
    acc[6] += __uint_as_float(v.w << 16);
    acc[7] += __uint_as_float(v.w & 0xffff0000u);
}

typedef const __attribute__((address_space(1))) void* as1cv;
typedef __attribute__((address_space(3))) void* as3v;
// async gather: per-lane global address, wave-uniform LDS base (+lane*16 by HW)
__device__ __forceinline__ void gload16(const void* g, void* l) {
    __builtin_amdgcn_global_load_lds((as1cv)g, (as3v)l, 16, 0, 0);
}

__device__ __forceinline__ short8 load_frag(const unsigned short* __restrict__ wl, int frag, int lane) {
    union { uint4 u; short8 s; } c;
    c.u = *(const uint4*)(wl + ((size_t)(frag * 64 + lane)) * 8);
    return c.s;
}

__device__ __forceinline__ void split8(const float* v, short8& hi, short8& lo) {
#pragma unroll
    for (int j = 0; j < 8; ++j) {
        unsigned short h = f2bf(v[j]);
        hi[j] = (short)h;
        lo[j] = (short)f2bf(v[j] - bf2f(h));
    }
}

// Fused GIN layer, WAVE-PRIVATE (no __syncthreads, waves fully independent):
// each wave aggregates 16 consecutive nodes (8 pairs, identical gather pipeline
// to the verified agg_kernel) into a 2 KB swizzled bf16 z-tile in LDS, then does
// the whole 16-node MLP in-wave (all 4 output quadrants). t redistributes through
// the reused 4 KB gather ring (f32, XOR-swizzled). z never touches global memory.
// Arithmetic order bit-identical to the verified split path.
// LDS 24 KB/block -> 6 blocks/CU.
__global__ __launch_bounds__(256) void fused_wave_kernel(
    const unsigned short* __restrict__ hin, unsigned short* __restrict__ hout,
    const int2* __restrict__ meta, const int* __restrict__ esrc,
    const unsigned short* __restrict__ wl,
    const float* __restrict__ b1, const float* __restrict__ b2) {
    __shared__ char ringbuf[4][4096];              // 16 KB: gather ring / f32 tbuf
    __shared__ unsigned short ztbuf[4][16 * DIM];  // 8 KB: bf16 z tiles (swizzled)
    const int lane = threadIdx.x & 63;
    const int wv = threadIdx.x >> 6;
    const int grp = lane >> 3;
    const int sub = lane & 7;
    const int m = lane & 15;
    const int quad = lane >> 4;
    const int wave_id = (blockIdx.x * blockDim.x + threadIdx.x) >> 6;
    const int n_waves = (gridDim.x * blockDim.x) >> 6;
    char* ring = ringbuf[wv];
    unsigned short* zt = ztbuf[wv];
    const char* hb = (const char*)hin;

    float b1v[4], b2v[4];
#pragma unroll
    for (int nt = 0; nt < 4; ++nt) {
        b1v[nt] = b1[nt * 16 + m];
        b2v[nt] = b2[nt * 16 + m];
    }

    for (int tile = wave_id; tile < MTILES; tile += n_waves) {
        const int node0 = tile * 16;

        // ---- aggregation: 8 pairs = 16 nodes, z -> swizzled LDS tile
        for (int p = 0; p < 8; ++p) {
            const int iA = node0 + 2 * p;
            const int iB = iA + 1;
            const int2 mA = meta[iA];
            const int2 mB = meta[iB];
            const float selfA = bf2f(hin[(size_t)iA * DIM + lane]);
            const float selfB = bf2f(hin[(size_t)iB * DIM + lane]);
            const int nA = mA.y, nB = mB.y;
            const int* eA = esrc + mA.x + grp;
            const int* eB = esrc + mB.x + grp;
            const int nb = ((nA > nB) ? nA : nB) >> 3;  // batches of 8 edges

            float accA[8] = {0.f, 0.f, 0.f, 0.f, 0.f, 0.f, 0.f, 0.f};
            float accB[8] = {0.f, 0.f, 0.f, 0.f, 0.f, 0.f, 0.f, 0.f};

            if (nb > 0) {
                int o;
                o = (0 < nA) ? 0 : 0;
                int ia0 = eA[o]; ia0 = (0 < nA) ? ia0 : DUMMY;
                int ib0 = eB[o]; ib0 = (0 < nB) ? ib0 : DUMMY;
                o = (8 < nA) ? 8 : 0;
                int ia1 = eA[o]; ia1 = (8 < nA) ? ia1 : DUMMY;
                o = (8 < nB) ? 8 : 0;
                int ib1 = eB[o]; ib1 = (8 < nB) ? ib1 : DUMMY;
                // all prior DS reads (prev pair reduce / prev tile MLP) must
                // retire before the async gathers overwrite ring
                asm volatile("s_waitcnt lgkmcnt(0)" ::: "memory");
                gload16(hb + ((size_t)(unsigned)ia0 << 7) + (sub << 4), ring);
                gload16(hb + ((size_t)(unsigned)ib0 << 7) + (sub << 4), ring + 2048);
                if (nb > 1) {
                    gload16(hb + ((size_t)(unsigned)ia1 << 7) + (sub << 4), ring + 1024);
                    gload16(hb + ((size_t)(unsigned)ib1 << 7) + (sub << 4), ring + 3072);
                }
                asm volatile("" ::: "memory");
                int t8 = 16;
                int oA = (t8 < nA) ? t8 : 0;
                int oB = (t8 < nB) ? t8 : 0;
                int nxA = eA[oA]; nxA = (t8 < nA) ? nxA : DUMMY;
                int nxB = eB[oB]; nxB = (t8 < nB) ? nxB : DUMMY;

                for (int b = 0; b < nb; ++b) {
                    if (b + 1 < nb) asm volatile("s_waitcnt vmcnt(4)" ::: "memory");
                    else            asm volatile("s_waitcnt vmcnt(2)" ::: "memory");
                    const int s = (b & 1) << 10;
                    uint4 va = *(const uint4*)(ring + s + lane * 16);
                    uint4 vb = *(const uint4*)(ring + 2048 + s + lane * 16);
                    acc8(accA, va);
                    acc8(accB, vb);
                    if (b + 2 < nb) {
                        asm volatile("s_waitcnt lgkmcnt(0)" ::: "memory");
                        gload16(hb + ((size_t)(unsigned)nxA << 7) + (sub << 4), ring + s);
                        gload16(hb + ((size_t)(unsigned)nxB << 7) + (sub << 4), ring + 2048 + s);
                        asm volatile("" ::: "memory");
                        t8 = 8 * (b + 3);
                        oA = (t8 < nA) ? t8 : 0;
                        oB = (t8 < nB) ? t8 : 0;
                        nxA = eA[oA]; nxA = (t8 < nA) ? nxA : DUMMY;
                        nxB = eB[oB]; nxB = (t8 < nB) ? nxB : DUMMY;
                    }
                }
            }

            // cross-group reduce through ring (gathers drained; 2 outstanding
            // vmem are VGPR-dest idx loads)
            float* zbA = (float*)ring;
            float* zbB = (float*)(ring + 2048);
            *((float4*)&zbA[grp * 64 + sub * 8 + 0]) = make_float4(accA[0], accA[1], accA[2], accA[3]);
            *((float4*)&zbA[grp * 64 + sub * 8 + 4]) = make_float4(accA[4], accA[5], accA[6], accA[7]);
            *((float4*)&zbB[grp * 64 + sub * 8 + 0]) = make_float4(accB[0], accB[1], accB[2], accB[3]);
            *((float4*)&zbB[grp * 64 + sub * 8 + 4]) = make_float4(accB[4], accB[5], accB[6], accB[7]);
            __builtin_amdgcn_wave_barrier();
            float zA = selfA, zB = selfB;
#pragma unroll
            for (int g = 0; g < 8; ++g) {
                zA += zbA[g * 64 + lane];
                zB += zbB[g * 64 + lane];
            }
            const int rA = 2 * p;
            const int rB = rA + 1;
            zt[rA * DIM + (lane ^ ((rA & 7) << 3))] = f2bf(zA);
            zt[rB * DIM + (lane ^ ((rB & 7) << 3))] = f2bf(zB);
            __builtin_amdgcn_wave_barrier();
        }

        // ---- in-wave MLP for the 16-node tile (ring reused as f32 tbuf)
        short8 a1f[2];
#pragma unroll
        for (int kf = 0; kf < 2; ++kf) {
            const int c = (kf * 32 + quad * 8) ^ ((m & 7) << 3);
            union { uint4 u; short8 s; } cu;
            cu.u = *(const uint4*)(zt + m * DIM + c);
            a1f[kf] = cu.s;
        }
        float* tb = (float*)ring;
#pragma unroll
        for (int nt = 0; nt < 4; ++nt) {
            short8 bhi0 = load_frag(wl, 0 + nt * 2 + 0, lane);
            short8 blo0 = load_frag(wl, 8 + nt * 2 + 0, lane);
            short8 bhi1 = load_frag(wl, 0 + nt * 2 + 1, lane);
            short8 blo1 = load_frag(wl, 8 + nt * 2 + 1, lane);
            float4v acc1 = {};
            acc1 = __builtin_amdgcn_mfma_f32_16x16x32_bf16(a1f[0], bhi0, acc1, 0, 0, 0);
            acc1 = __builtin_amdgcn_mfma_f32_16x16x32_bf16(a1f[0], blo0, acc1, 0, 0, 0);
            acc1 = __builtin_amdgcn_mfma_f32_16x16x32_bf16(a1f[1], bhi1, acc1, 0, 0, 0);
            acc1 = __builtin_amdgcn_mfma_f32_16x16x32_bf16(a1f[1], blo1, acc1, 0, 0, 0);
#pragma unroll
            for (int r = 0; r < 4; ++r) {
                const int row = quad * 4 + r;
                tb[row * 64 + ((nt * 16 + m) ^ ((row & 7) << 3))] = fmaxf(acc1[r] + b1v[nt], 0.f);
            }
        }
        __builtin_amdgcn_wave_barrier();

        short8 a2hi[2], a2lo[2];
#pragma unroll
        for (int kf = 0; kf < 2; ++kf) {
            const int c = (kf * 32 + quad * 8) ^ ((m & 7) << 3);
            float v[8];
            *(float4*)(v + 0) = *(const float4*)(tb + m * 64 + c + 0);
            *(float4*)(v + 4) = *(const float4*)(tb + m * 64 + c + 4);
            split8(v, a2hi[kf], a2lo[kf]);
        }
        __builtin_amdgcn_wave_barrier();

#pragma unroll
        for (int nt = 0; nt < 4; ++nt) {
            short8 bhi0 = load_frag(wl, 16 + nt * 2 + 0, lane);
            short8 blo0 = load_frag(wl, 24 + nt * 2 + 0, lane);
            short8 bhi1 = load_frag(wl, 16 + nt * 2 + 1, lane);
            short8 blo1 = load_frag(wl, 24 + nt * 2 + 1, lane);
            float4v acc2 = {};
            acc2 = __builtin_amdgcn_mfma_f32_16x16x32_bf16(a2hi[0], bhi0, acc2, 0, 0, 0);
            acc2 = __builtin_amdgcn_mfma_f32_16x16x32_bf16(a2hi[0], blo0, acc2, 0, 0, 0);
            acc2 = __builtin_amdgcn_mfma_f32_16x16x32_bf16(a2lo[0], bhi0, acc2, 0, 0, 0);
            acc2 = __builtin_amdgcn_mfma_f32_16x16x32_bf16(a2hi[1], bhi1, acc2, 0, 0, 0);
            acc2 = __builtin_amdgcn_mfma_f32_16x16x32_bf16(a2hi[1], blo1, acc2, 0, 0, 0);
            acc2 = __builtin_amdgcn_mfma_f32_16x16x32_bf16(a2lo[1], bhi1, acc2, 0, 0, 0);
#pragma unroll
            for (int r = 0; r < 4; ++r) {
                float o = acc2[r] + b2v[nt];
                hout[((size_t)(node0 + quad * 4 + r)) * DIM + nt * 16 + m] = f2bf(o);
            }
        }
        // next tile's pair-0 prologue lgkmcnt(0) orders ring/zt reuse
    }
}

// Block (4 waves) per graph: binary-search node range, mean-pool (bf16 in), readout MLP.
__global__ __launch_bounds__(256) void pool_mlp_kernel(
    const unsigned short* __restrict__ h, const int* __restrict__ batch,
    const float* __restrict__ mW1, const float* __restrict__ mb1,
    const float* __restrict__ mW2, const float* __restrict__ mb2,
    float* __restrict__ out, int n_nodes) {
    __shared__ float part[4][DIM];
    const int g = blockIdx.x;
    const int lane = threadIdx.x & 63;
    const int w = threadIdx.x >> 6;

    int lo = 0, hi = n_nodes;
    while (lo < hi) {
        int mid = (lo + hi) >> 1;
        if (batch[mid] < g) lo = mid + 1; else hi = mid;
    }
    const int s0 = lo;
    hi = n_nodes;
    while (lo < hi) {
        int mid = (lo + hi) >> 1;
        if (batch[mid] < g + 1) lo = mid + 1; else hi = mid;
    }
    const int e0 = lo;

    float acc = 0.f;
    int i = s0 + w;
    for (; i + 12 < e0; i += 16) {
        float v0 = bf2f(h[i * DIM + lane]);
        float v1 = bf2f(h[(i + 4) * DIM + lane]);
        float v2 = bf2f(h[(i + 8) * DIM + lane]);
        float v3 = bf2f(h[(i + 12) * DIM + lane]);
        acc += (v0 + v1) + (v2 + v3);
    }
    for (; i < e0; i += 4) acc += bf2f(h[i * DIM + lane]);
    part[w][lane] = acc;
    __syncthreads();

    if (w == 0) {
        acc = (part[0][lane] + part[1][lane]) + (part[2][lane] + part[3][lane]);
        float cntf = (float)(e0 - s0);
        acc /= fmaxf(cntf, 1.f);

        float t = mb1[lane];
#pragma unroll
        for (int d = 0; d < DIM; ++d) {
            float zd = __shfl(acc, d);
            t = fmaf(zd, mW1[d * DIM + lane], t);
        }
        t = fmaxf(t, 0.f);
        float o = mb2[lane];
#pragma unroll
        for (int d = 0; d < DIM; ++d) {
            float rd = __shfl(t, d);
            o = fmaf(rd, mW2[d * DIM + lane], o);
        }
        out[g * DIM + lane] = o;
    }
}

extern "C" void kernel_launch(void* const* d_in, const int* in_sizes, int n_in,
                              void* d_out, int out_size, void* d_ws, size_t ws_size,
                              hipStream_t stream) {
    const float* x   = (const float*)d_in[0];
    const int*   ei  = (const int*)d_in[1];
    const int*   bat = (const int*)d_in[2];
    const float* Ws1 = (const float*)d_in[3];
    const float* bs1 = (const float*)d_in[4];
    const float* Ws2 = (const float*)d_in[5];
    const float* bs2 = (const float*)d_in[6];
    const float* mW1 = (const float*)d_in[7];
    const float* mb1 = (const float*)d_in[8];
    const float* mW2 = (const float*)d_in[9];
    const float* mb2 = (const float*)d_in[10];
    float* out = (float*)d_out;

    char* ws = (char*)d_ws;
    size_t off = 0;
    auto alloc = [&](size_t bytes) {
        void* p = ws + off;
        off += (bytes + 255) & ~(size_t)255;
        return p;
    };
    int*  esrc    = (int*)alloc((size_t)NB2 * CAP2 * 4);       // 10.0 MB
    int2* meta    = (int2*)alloc((size_t)N_NODES * 8);         // 0.8 MB
    unsigned short* hbfA = (unsigned short*)alloc(((size_t)N_NODES + 1) * DIM * 2);
    unsigned short* hbfB = (unsigned short*)alloc(((size_t)N_NODES + 1) * DIM * 2);
    int*  bcursor = (int*)alloc((size_t)NB2 * 4);
    unsigned short* wpk = (unsigned short*)alloc((size_t)N_LAYERS * 32 * 64 * 8 * 2);  // 160 KB
    int*   pairbuf = (int*)alloc((size_t)NB2 * SUBCAP2 * 4);   // 7.2 MB

    const int* src = ei;
    const int* dst = ei + N_EDGES;

    // merged setup: cvt + prepack + bcursor zero + dummy rows (1 dispatch)
    setup_kernel<<<SETUP_BLOCKS, 256, 0, stream>>>(
        (const float4*)x, (ushort4*)hbfA, Ws1, Ws2, wpk, bcursor, hbfA, hbfB);

    // CSR build: tile-binning with run reservation -> per-bucket padded CSR
    bin_kernel<<<NTILE, 256, 0, stream>>>(src, dst, bcursor, pairbuf);
    csr_kernel<<<NB2, 512, 0, stream>>>(bcursor, pairbuf, esrc, meta);

    const unsigned short* hin = hbfA;
    unsigned short* hout = hbfB;
    for (int l = 0; l < N_LAYERS; ++l) {
        // 1536 blocks x 4 waves = 6144 waves over 6250 tiles (grid-strided)
        fused_wave_kernel<<<1536, 256, 0, stream>>>(hin, hout, meta, esrc,
                                                    wpk + (size_t)l * 32 * 64 * 8,
                                                    bs1 + (size_t)l * DIM,
                                                    bs2 + (size_t)l * DIM);
        hin = hout;
        hout = (hout == hbfA) ? hbfB : hbfA;
    }
    pool_mlp_kernel<<<N_GRAPHS, 256, 0, stream>>>(hin, bat, mW1, mb1, mW2, mb2, out, N_NODES);
}

// Round 6
// 371.765 us; speedup vs baseline: 1.3031x; 1.3031x over previous
//
#include <hip/hip_runtime.h>
#include <hip/hip_bf16.h>

#define N_NODES 100000
#define N_EDGES 1600000
#define DIM 64
#define N_LAYERS 5
#define N_GRAPHS 256

#define NB2 391        // coarse buckets of 256 nodes (391*256 = 100096 >= 100000)
#define BSH 8          // bucket shift: node>>8
#define BMSK 255       // local id mask
#define SUBCAP2 4608   // per-bucket pair capacity: mean 4096, sigma ~64 (+8 sigma)
#define CAP2 6400      // esrc region per bucket (padded CSR: mean 4992, +19 sigma)
#define DUMMY N_NODES  // dummy node id; its h row is kept zero
#define TILE 3200      // edges per binning workgroup
#define NTILE 500      // 500 * 3200 = 1.6M
#define MTILES (N_NODES / 16)  // 6250 node-tiles for the MFMA MLP

#define CVT_BLOCKS 6250            // 6250*256*4 = 1.6M float4 = N_NODES*DIM
#define PREPACK_BLOCKS 40          // 40*256 = 10240 = N_LAYERS*32*64
#define SETUP_BLOCKS (CVT_BLOCKS + PREPACK_BLOCKS + 1)

typedef __attribute__((ext_vector_type(8))) short short8;
typedef __attribute__((ext_vector_type(4))) float float4v;

// bf16 helpers (bit-level, RNE)
__device__ __forceinline__ unsigned short f2bf(float f) {
    unsigned int u = __float_as_uint(f);
    unsigned int r = (u + 0x7fffu + ((u >> 16) & 1u)) >> 16;
    return (unsigned short)r;
}
__device__ __forceinline__ float bf2f(unsigned short b) {
    return __uint_as_float(((unsigned int)b) << 16);
}

// Merged setup: cvt (blocks 0..6249) | prepack (blocks 6250..6289) |
// bcursor-zero + dummy-row-zero (block 6290). All independent; one dispatch.
__global__ __launch_bounds__(256) void setup_kernel(
    const float4* __restrict__ x, ushort4* __restrict__ hb,
    const float* __restrict__ Ws1, const float* __restrict__ Ws2,
    unsigned short* __restrict__ wpk, int* __restrict__ bcursor,
    unsigned short* __restrict__ hA, unsigned short* __restrict__ hB) {
    const int b = blockIdx.x;
    const int tid = threadIdx.x;
    if (b < CVT_BLOCKS) {
        int i = b * 256 + tid;  // exactly N_NODES*DIM/4
        float4 v = x[i];
        ushort4 o;
        o.x = f2bf(v.x); o.y = f2bf(v.y); o.z = f2bf(v.z); o.w = f2bf(v.w);
        hb[i] = o;
    } else if (b < CVT_BLOCKS + PREPACK_BLOCKS) {
        int t = (b - CVT_BLOCKS) * 256 + tid;  // < N_LAYERS*32*64
        int lane = t & 63;
        int frag = (t >> 6) & 31;
        int l = t >> 11;
        int kf = frag & 1;
        int nt = (frag >> 1) & 3;
        int split = (frag >> 3) & 1;
        int mat = (frag >> 4) & 1;
        const float* W = (mat ? Ws2 : Ws1) + (size_t)l * DIM * DIM;
        unsigned short outv[8];
#pragma unroll
        for (int j = 0; j < 8; ++j) {
            int k = kf * 32 + ((lane >> 4) << 3) + j;
            int n = nt * 16 + (lane & 15);
            float v = W[k * DIM + n];
            unsigned short hi = f2bf(v);
            outv[j] = split ? f2bf(v - bf2f(hi)) : hi;
        }
        ushort4* dst = (ushort4*)(wpk + ((size_t)(l * 32 + frag) * 64 + lane) * 8);
        dst[0] = make_ushort4(outv[0], outv[1], outv[2], outv[3]);
        dst[1] = make_ushort4(outv[4], outv[5], outv[6], outv[7]);
    } else {
        for (int l = tid; l < NB2; l += 256) bcursor[l] = 0;
        if (tid < DIM) {
            hA[(size_t)DUMMY * DIM + tid] = 0;
            hB[(size_t)DUMMY * DIM + tid] = 0;
        }
    }
}

// Phase A: tile-binning with run reservation (one global atomic per bucket per tile).
__global__ __launch_bounds__(256) void bin_kernel(
    const int* __restrict__ src, const int* __restrict__ dst,
    int* __restrict__ bcursor, int* __restrict__ pairbuf) {
    __shared__ int hcnt[NB2];
    __shared__ int gbase[NB2];
    __shared__ int lcur[NB2];
    const int tid = threadIdx.x;
    const int base = blockIdx.x * TILE;

    for (int l = tid; l < NB2; l += 256) { hcnt[l] = 0; lcur[l] = 0; }
    __syncthreads();
    for (int j = tid; j < TILE; j += 256) {
        int d = dst[base + j];
        atomicAdd(&hcnt[d >> BSH], 1);
    }
    __syncthreads();
    for (int l = tid; l < NB2; l += 256)
        gbase[l] = atomicAdd(&bcursor[l], hcnt[l]);
    __syncthreads();
    for (int j = tid; j < TILE; j += 256) {
        int s = src[base + j];
        int d = dst[base + j];
        int b = d >> BSH;
        int r = atomicAdd(&lcur[b], 1);
        int pos = gbase[b] + r;
        if (pos < SUBCAP2) pairbuf[b * SUBCAP2 + pos] = (s << BSH) | (d & BMSK);
    }
}

// Phase B: one 512-thread WG per 256-node bucket. Count -> padded scan -> scatter.
__global__ __launch_bounds__(512) void csr_kernel(
    const int* __restrict__ bcursor, const int* __restrict__ pairbuf,
    int* __restrict__ esrc, int2* __restrict__ meta) {
    __shared__ int lcnt[256];
    __shared__ int loff[256];
    __shared__ int lcur[256];
    __shared__ int s2[256];
    const int b = blockIdx.x;
    const int tid = threadIdx.x;
    int ec = bcursor[b];
    if (ec > SUBCAP2) ec = SUBCAP2;
    const int* pp = pairbuf + b * SUBCAP2;

    if (tid < 256) lcnt[tid] = 0;
    __syncthreads();
    for (int j = tid; j < ec; j += 512) atomicAdd(&lcnt[pp[j] & BMSK], 1);
    __syncthreads();

    if (tid < 256) s2[tid] = (lcnt[tid] + 7) & ~7;
    __syncthreads();
    for (int off = 1; off < 256; off <<= 1) {
        int v = (tid >= off && tid < 256) ? s2[tid - off] : 0;
        __syncthreads();
        if (tid < 256) s2[tid] += v;
        __syncthreads();
    }
    if (tid < 256) {
        int c = (lcnt[tid] + 7) & ~7;
        int exc = s2[tid] - c;
        loff[tid] = exc;
        lcur[tid] = exc;
    }
    __syncthreads();

    int* eb = esrc + (size_t)b * CAP2;
    for (int l = tid; l < 256; l += 512) {
        int st = loff[l];
        int cn = lcnt[l];
        int cp = (cn + 7) & ~7;
        int node = b * 256 + l;
        if (node < N_NODES) meta[node] = make_int2(b * CAP2 + st, cp);
        for (int j = cn; j < cp; ++j) eb[st + j] = DUMMY;
    }
    __syncthreads();

    for (int j = tid; j < ec; j += 512) {
        int p = pp[j];
        int pos = atomicAdd(&lcur[p & BMSK], 1);
        eb[pos] = p >> BSH;
    }
}

__device__ __forceinline__ void acc8(float* acc, uint4 v) {
    acc[0] += __uint_as_float(v.x << 16);
    acc[1] += __uint_as_float(v.x & 0xffff0000u);
    acc[2] += __uint_as_float(v.y << 16);
    acc[3] += __uint_as_float(v.y & 0xffff0000u);
    acc[4] += __uint_as_float(v.z << 16);
    acc[5] += __uint_as_float(v.z & 0xffff0000u);
    acc[6] += __uint_as_float(v.w << 16);
    acc[7] += __uint_as_float(v.w & 0xffff0000u);
}

typedef const __attribute__((address_space(1))) void* as1cv;
typedef __attribute__((address_space(3))) void* as3v;
// async gather: per-lane global address, wave-uniform LDS base (+lane*16 by HW)
__device__ __forceinline__ void gload16(const void* g, void* l) {
    __builtin_amdgcn_global_load_lds((as1cv)g, (as3v)l, 16, 0, 0);
}

// Aggregation: z_i = h_i + sum_j h_j, h rows bf16 (128 B).
// global_load_lds double-buffered ring; both this and the register-gather
// version land at ~5.4 TB/s effective -- system random-gather ceiling.
__global__ __launch_bounds__(256) void agg_kernel(
    const unsigned short* __restrict__ hin, unsigned short* __restrict__ z,
    const int2* __restrict__ meta, const int* __restrict__ esrc, int n_nodes) {
    __shared__ char scratch[4][4096];  // 16 KB
    const int lane = threadIdx.x & 63;
    const int wv = threadIdx.x >> 6;
    const int grp = lane >> 3;
    const int sub = lane & 7;
    const int wave_id = (blockIdx.x * blockDim.x + threadIdx.x) >> 6;
    const int n_waves = (gridDim.x * blockDim.x) >> 6;
    char* ring = scratch[wv];
    const char* hb = (const char*)hin;

    for (int ii = wave_id; 2 * ii < n_nodes; ii += n_waves) {
        const int iA = 2 * ii;
        const int iB = iA + 1;
        const int2 mA = meta[iA];
        const int2 mB = meta[iB];
        const float selfA = bf2f(hin[(size_t)iA * DIM + lane]);
        const float selfB = bf2f(hin[(size_t)iB * DIM + lane]);
        const int nA = mA.y, nB = mB.y;
        const int* eA = esrc + mA.x + grp;
        const int* eB = esrc + mB.x + grp;
        const int nb = ((nA > nB) ? nA : nB) >> 3;  // batches of 8 edges

        float accA[8] = {0.f, 0.f, 0.f, 0.f, 0.f, 0.f, 0.f, 0.f};
        float accB[8] = {0.f, 0.f, 0.f, 0.f, 0.f, 0.f, 0.f, 0.f};

        if (nb > 0) {
            int o;
            o = (0 < nA) ? 0 : 0;
            int ia0 = eA[o]; ia0 = (0 < nA) ? ia0 : DUMMY;
            int ib0 = eB[o]; ib0 = (0 < nB) ? ib0 : DUMMY;
            o = (8 < nA) ? 8 : 0;
            int ia1 = eA[o]; ia1 = (8 < nA) ? ia1 : DUMMY;
            o = (8 < nB) ? 8 : 0;
            int ib1 = eB[o]; ib1 = (8 < nB) ? ib1 : DUMMY;
            asm volatile("s_waitcnt lgkmcnt(0)" ::: "memory");
            gload16(hb + ((size_t)(unsigned)ia0 << 7) + (sub << 4), ring);
            gload16(hb + ((size_t)(unsigned)ib0 << 7) + (sub << 4), ring + 2048);
            if (nb > 1) {
                gload16(hb + ((size_t)(unsigned)ia1 << 7) + (sub << 4), ring + 1024);
                gload16(hb + ((size_t)(unsigned)ib1 << 7) + (sub << 4), ring + 3072);
            }
            asm volatile("" ::: "memory");
            int t8 = 16;
            int oA = (t8 < nA) ? t8 : 0;
            int oB = (t8 < nB) ? t8 : 0;
            int nxA = eA[oA]; nxA = (t8 < nA) ? nxA : DUMMY;
            int nxB = eB[oB]; nxB = (t8 < nB) ? nxB : DUMMY;

            for (int b = 0; b < nb; ++b) {
                if (b + 1 < nb) asm volatile("s_waitcnt vmcnt(4)" ::: "memory");
                else            asm volatile("s_waitcnt vmcnt(2)" ::: "memory");
                const int s = (b & 1) << 10;
                uint4 va = *(const uint4*)(ring + s + lane * 16);
                uint4 vb = *(const uint4*)(ring + 2048 + s + lane * 16);
                acc8(accA, va);
                acc8(accB, vb);
                if (b + 2 < nb) {
                    asm volatile("s_waitcnt lgkmcnt(0)" ::: "memory");
                    gload16(hb + ((size_t)(unsigned)nxA << 7) + (sub << 4), ring + s);
                    gload16(hb + ((size_t)(unsigned)nxB << 7) + (sub << 4), ring + 2048 + s);
                    asm volatile("" ::: "memory");
                    t8 = 8 * (b + 3);
                    oA = (t8 < nA) ? t8 : 0;
                    oB = (t8 < nB) ? t8 : 0;
                    nxA = eA[oA]; nxA = (t8 < nA) ? nxA : DUMMY;
                    nxB = eB[oB]; nxB = (t8 < nB) ? nxB : DUMMY;
                }
            }
        }

        float* zbA = (float*)ring;
        float* zbB = (float*)(ring + 2048);
        *((float4*)&zbA[grp * 64 + sub * 8 + 0]) = make_float4(accA[0], accA[1], accA[2], accA[3]);
        *((float4*)&zbA[grp * 64 + sub * 8 + 4]) = make_float4(accA[4], accA[5], accA[6], accA[7]);
        *((float4*)&zbB[grp * 64 + sub * 8 + 0]) = make_float4(accB[0], accB[1], accB[2], accB[3]);
        *((float4*)&zbB[grp * 64 + sub * 8 + 4]) = make_float4(accB[4], accB[5], accB[6], accB[7]);
        __builtin_amdgcn_wave_barrier();
        float zA = selfA, zB = selfB;
#pragma unroll
        for (int g = 0; g < 8; ++g) {
            zA += zbA[g * 64 + lane];
            zB += zbB[g * 64 + lane];
        }
        z[(size_t)iA * DIM + lane] = f2bf(zA);
        z[(size_t)iB * DIM + lane] = f2bf(zB);
        __builtin_amdgcn_wave_barrier();
    }
}

__device__ __forceinline__ short8 load_frag(const unsigned short* __restrict__ wl, int frag, int lane) {
    union { uint4 u; short8 s; } c;
    c.u = *(const uint4*)(wl + ((size_t)(frag * 64 + lane)) * 8);
    return c.s;
}

__device__ __forceinline__ void split8(const float* v, short8& hi, short8& lo) {
#pragma unroll
    for (int j = 0; j < 8; ++j) {
        unsigned short h = f2bf(v[j]);
        hi[j] = (short)h;
        lo[j] = (short)f2bf(v[j] - bf2f(h));
    }
}

// MFMA MLP: h = relu(z@W1+b1)@W2+b2 ; z bf16 in, h bf16 out.
__global__ __launch_bounds__(256) void mlp_mfma_kernel(
    const unsigned short* __restrict__ z, unsigned short* __restrict__ hout,
    const unsigned short* __restrict__ wl,
    const float* __restrict__ b1, const float* __restrict__ b2) {
    __shared__ float tbuf[4][16][68];
    const int lane = threadIdx.x & 63;
    const int wv = threadIdx.x >> 6;
    const int m = lane & 15;
    const int quad = lane >> 4;
    const int wave_id = (blockIdx.x * blockDim.x + threadIdx.x) >> 6;
    const int n_waves = (gridDim.x * blockDim.x) >> 6;

    float b1v[4], b2v[4];
#pragma unroll
    for (int nt = 0; nt < 4; ++nt) {
        b1v[nt] = b1[nt * 16 + m];
        b2v[nt] = b2[nt * 16 + m];
    }

    for (int tile = wave_id; tile < MTILES; tile += n_waves) {
        const int node0 = tile * 16;

        short8 a1[2];
#pragma unroll
        for (int kf = 0; kf < 2; ++kf) {
            union { uint4 u; short8 s; } c;
            c.u = *(const uint4*)(z + ((size_t)(node0 + m)) * DIM + kf * 32 + quad * 8);
            a1[kf] = c.s;
        }

        float4v acc1[4] = {};
#pragma unroll
        for (int nt = 0; nt < 4; ++nt) {
#pragma unroll
            for (int kf = 0; kf < 2; ++kf) {
                short8 bhi = load_frag(wl, ((0 * 2 + 0) * 4 + nt) * 2 + kf, lane);
                short8 blo = load_frag(wl, ((0 * 2 + 1) * 4 + nt) * 2 + kf, lane);
                acc1[nt] = __builtin_amdgcn_mfma_f32_16x16x32_bf16(a1[kf], bhi, acc1[nt], 0, 0, 0);
                acc1[nt] = __builtin_amdgcn_mfma_f32_16x16x32_bf16(a1[kf], blo, acc1[nt], 0, 0, 0);
            }
        }

#pragma unroll
        for (int nt = 0; nt < 4; ++nt) {
#pragma unroll
            for (int r = 0; r < 4; ++r) {
                float tv = acc1[nt][r] + b1v[nt];
                tbuf[wv][quad * 4 + r][nt * 16 + m] = fmaxf(tv, 0.f);
            }
        }
        __builtin_amdgcn_wave_barrier();

        short8 a2hi[2], a2lo[2];
#pragma unroll
        for (int kf = 0; kf < 2; ++kf) {
            const float4* tp = (const float4*)&tbuf[wv][m][kf * 32 + quad * 8];
            float4 t0 = tp[0];
            float4 t1 = tp[1];
            float v[8] = {t0.x, t0.y, t0.z, t0.w, t1.x, t1.y, t1.z, t1.w};
            split8(v, a2hi[kf], a2lo[kf]);
        }
        __builtin_amdgcn_wave_barrier();

        float4v acc2[4] = {};
#pragma unroll
        for (int nt = 0; nt < 4; ++nt) {
#pragma unroll
            for (int kf = 0; kf < 2; ++kf) {
                short8 bhi = load_frag(wl, ((1 * 2 + 0) * 4 + nt) * 2 + kf, lane);
                short8 blo = load_frag(wl, ((1 * 2 + 1) * 4 + nt) * 2 + kf, lane);
                acc2[nt] = __builtin_amdgcn_mfma_f32_16x16x32_bf16(a2hi[kf], bhi, acc2[nt], 0, 0, 0);
                acc2[nt] = __builtin_amdgcn_mfma_f32_16x16x32_bf16(a2hi[kf], blo, acc2[nt], 0, 0, 0);
                acc2[nt] = __builtin_amdgcn_mfma_f32_16x16x32_bf16(a2lo[kf], bhi, acc2[nt], 0, 0, 0);
            }
        }

#pragma unroll
        for (int nt = 0; nt < 4; ++nt) {
#pragma unroll
            for (int r = 0; r < 4; ++r) {
                float o = acc2[nt][r] + b2v[nt];
                hout[((size_t)(node0 + quad * 4 + r)) * DIM + nt * 16 + m] = f2bf(o);
            }
        }
    }
}

// Block (4 waves) per graph: binary-search node range, mean-pool (bf16 in), readout MLP.
__global__ __launch_bounds__(256) void pool_mlp_kernel(
    const unsigned short* __restrict__ h, const int* __restrict__ batch,
    const float* __restrict__ mW1, const float* __restrict__ mb1,
    const float* __restrict__ mW2, const float* __restrict__ mb2,
    float* __restrict__ out, int n_nodes) {
    __shared__ float part[4][DIM];
    const int g = blockIdx.x;
    const int lane = threadIdx.x & 63;
    const int w = threadIdx.x >> 6;

    int lo = 0, hi = n_nodes;
    while (lo < hi) {
        int mid = (lo + hi) >> 1;
        if (batch[mid] < g) lo = mid + 1; else hi = mid;
    }
    const int s0 = lo;
    hi = n_nodes;
    while (lo < hi) {
        int mid = (lo + hi) >> 1;
        if (batch[mid] < g + 1) lo = mid + 1; else hi = mid;
    }
    const int e0 = lo;

    float acc = 0.f;
    int i = s0 + w;
    for (; i + 12 < e0; i += 16) {
        float v0 = bf2f(h[i * DIM + lane]);
        float v1 = bf2f(h[(i + 4) * DIM + lane]);
        float v2 = bf2f(h[(i + 8) * DIM + lane]);
        float v3 = bf2f(h[(i + 12) * DIM + lane]);
        acc += (v0 + v1) + (v2 + v3);
    }
    for (; i < e0; i += 4) acc += bf2f(h[i * DIM + lane]);
    part[w][lane] = acc;
    __syncthreads();

    if (w == 0) {
        acc = (part[0][lane] + part[1][lane]) + (part[2][lane] + part[3][lane]);
        float cntf = (float)(e0 - s0);
        acc /= fmaxf(cntf, 1.f);

        float t = mb1[lane];
#pragma unroll
        for (int d = 0; d < DIM; ++d) {
            float zd = __shfl(acc, d);
            t = fmaf(zd, mW1[d * DIM + lane], t);
        }
        t = fmaxf(t, 0.f);
        float o = mb2[lane];
#pragma unroll
        for (int d = 0; d < DIM; ++d) {
            float rd = __shfl(t, d);
            o = fmaf(rd, mW2[d * DIM + lane], o);
        }
        out[g * DIM + lane] = o;
    }
}

extern "C" void kernel_launch(void* const* d_in, const int* in_sizes, int n_in,
                              void* d_out, int out_size, void* d_ws, size_t ws_size,
                              hipStream_t stream) {
    const float* x   = (const float*)d_in[0];
    const int*   ei  = (const int*)d_in[1];
    const int*   bat = (const int*)d_in[2];
    const float* Ws1 = (const float*)d_in[3];
    const float* bs1 = (const float*)d_in[4];
    const float* Ws2 = (const float*)d_in[5];
    const float* bs2 = (const float*)d_in[6];
    const float* mW1 = (const float*)d_in[7];
    const float* mb1 = (const float*)d_in[8];
    const float* mW2 = (const float*)d_in[9];
    const float* mb2 = (const float*)d_in[10];
    float* out = (float*)d_out;

    char* ws = (char*)d_ws;
    size_t off = 0;
    auto alloc = [&](size_t bytes) {
        void* p = ws + off;
        off += (bytes + 255) & ~(size_t)255;
        return p;
    };
    int*  esrc    = (int*)alloc((size_t)NB2 * CAP2 * 4);       // 10.0 MB
    int2* meta    = (int2*)alloc((size_t)N_NODES * 8);         // 0.8 MB
    unsigned short* hbfA = (unsigned short*)alloc(((size_t)N_NODES + 1) * DIM * 2);
    unsigned short* hbfB = (unsigned short*)alloc(((size_t)N_NODES + 1) * DIM * 2);
    int*  bcursor = (int*)alloc((size_t)NB2 * 4);
    unsigned short* wpk = (unsigned short*)alloc((size_t)N_LAYERS * 32 * 64 * 8 * 2);  // 160 KB
    int*   pairbuf = (int*)alloc((size_t)NB2 * SUBCAP2 * 4);   // 7.2 MB
    unsigned short* zbig = (unsigned short*)alloc((size_t)N_NODES * DIM * 2);  // 12.8 MB

    const int* src = ei;
    const int* dst = ei + N_EDGES;

    // merged setup: cvt + prepack + bcursor zero + dummy rows (1 dispatch)
    setup_kernel<<<SETUP_BLOCKS, 256, 0, stream>>>(
        (const float4*)x, (ushort4*)hbfA, Ws1, Ws2, wpk, bcursor, hbfA, hbfB);

    // CSR build: tile-binning with run reservation -> per-bucket padded CSR
    bin_kernel<<<NTILE, 256, 0, stream>>>(src, dst, bcursor, pairbuf);
    csr_kernel<<<NB2, 512, 0, stream>>>(bcursor, pairbuf, esrc, meta);

    const unsigned short* hin = hbfA;
    unsigned short* hout = hbfB;
    for (int l = 0; l < N_LAYERS; ++l) {
        agg_kernel<<<2048, 256, 0, stream>>>(hin, zbig, meta, esrc, N_NODES);
        mlp_mfma_kernel<<<2048, 256, 0, stream>>>(zbig, hout,
                                                  wpk + (size_t)l * 32 * 64 * 8,
                                                  bs1 + (size_t)l * DIM,
                                                  bs2 + (size_t)l * DIM);
        hin = hout;
        hout = (hout == hbfA) ? hbfB : hbfA;
    }
    pool_mlp_kernel<<<N_GRAPHS, 256, 0, stream>>>(hin, bat, mW1, mb1, mW2, mb2, out, N_NODES);
}